// Round 3
// baseline (67.920 us; speedup 1.0000x reference)
//
#include <hip/hip_runtime.h>
#include <hip/hip_bf16.h>

typedef __attribute__((ext_vector_type(8))) short bf16x8;
typedef __attribute__((ext_vector_type(4))) float f32x4;

#define D 1024
#define NROWS 4096          // B
#define SCALE_U 14.426950408889634f   // (1/T) * log2(e)
#define LN2 0.69314718055994530942f
#define NCC 16              // column chunks (grid.y) — one 256-col block each
#define BT 256              // block tile rows/cols
#define BK 32               // K slab per pipeline stage
#define NT 32               // D/BK K-tiles

// ---------------- workspace layout ----------------
// zn      : 8192*1024 bf16 (z1 rows pre-scaled by SCALE_U)   @ 0         (16 MiB)
// pmax    : 4096*16 f32                                      @ 16777216  (256 KiB)
// psum    : 4096*16 f32                                      @ 17039360  (256 KiB)
// diag    : 4096 f32                                         @ 17301504  (16 KiB)
// contrib : 4096 f32                                         @ 17317888  (16 KiB)

__device__ __forceinline__ unsigned short f2bf(float x) {
    __hip_bfloat16 h = __float2bfloat16(x);
    return *reinterpret_cast<unsigned short*>(&h);
}
__device__ __forceinline__ void gload16(const unsigned short* g, unsigned short* l) {
    __builtin_amdgcn_global_load_lds((const __attribute__((address_space(1))) void*)g,
                                     (__attribute__((address_space(3))) void*)l, 16, 0, 0);
}

// ---------- 1. row normalize + bf16 cast (z1 scaled by SCALE_U) ----------
__global__ __launch_bounds__(256) void nrm_kernel(const float* __restrict__ feat,
                                                  unsigned short* __restrict__ zn) {
    const int row = blockIdx.x;           // 0..8191
    const int tid = threadIdx.x;          // 256, 4 floats each
    const float4 v = reinterpret_cast<const float4*>(feat + (size_t)row * D)[tid];
    float ss = v.x * v.x + v.y * v.y + v.z * v.z + v.w * v.w;
#pragma unroll
    for (int off = 32; off > 0; off >>= 1) ss += __shfl_down(ss, off);
    __shared__ float red[4];
    const int lane = tid & 63, wid = tid >> 6;
    if (lane == 0) red[wid] = ss;
    __syncthreads();
    const float tot = red[0] + red[1] + red[2] + red[3];
    const float nrm = fmaxf(sqrtf(tot), 1e-8f);
    const float sc = ((row < NROWS) ? SCALE_U : 1.0f) / nrm;
    ushort4 o;
    o.x = f2bf(v.x * sc);
    o.y = f2bf(v.y * sc);
    o.z = f2bf(v.z * sc);
    o.w = f2bf(v.w * sc);
    reinterpret_cast<ushort4*>(zn + (size_t)row * D)[tid] = o;
}

// ---------- 2. Gram (u = logits*log2e) + fused LSE partials ----------
// 256x256 tile, 8 waves (2Mx4N), BK=32, 4-deep LDS ring, prefetch distance 3,
// counted vmcnt(12) at tile boundaries (never 0 in main loop), raw s_barrier.
// LDS per buf per operand: 128 superrows (2 rows) x 8 chunks(16B), swizzle
// phys = idx ^ (sr&7), idx = (row&1)*4 + chunk16. Pre-swizzled global source
// (linear LDS dest for global_load_lds) + swizzled ds_read: both-sides rule.
__global__ __launch_bounds__(512, 2) void gram_lse_kernel(const unsigned short* __restrict__ zn,
                                                          float* __restrict__ pmax,
                                                          float* __restrict__ psum,
                                                          float* __restrict__ diag) {
    __shared__ __align__(16) unsigned short lds[4][2][8192];   // 128 KiB

    const int rt  = blockIdx.x;       // 0..15 row tile
    const int cc  = blockIdx.y;       // 0..15 col tile
    const int tid = threadIdx.x;
    const int lane = tid & 63;
    const int wid  = tid >> 6;        // 0..7
    const int wm = wid >> 2, wn = wid & 3;
    const int l15 = lane & 15, g = lane >> 4;

    const unsigned short* z1 = zn;
    const unsigned short* z2 = zn + (size_t)NROWS * D;

    // ---- staging addressing (per-lane, inverse-swizzled global source) ----
    // wave-instr (wid,j) covers superrows seg*8..+8, seg = wid*2+j; lane l:
    // sr_local = l>>3, phys = l&7, idx = phys ^ sr_local, row = seg*16 + sr_local*2 + (idx>>2)
    const int sidx  = (lane & 7) ^ (lane >> 3);
    const int srow0 = wid * 32 + (lane >> 3) * 2 + (sidx >> 2);   // row for seg0 = wid*2
    const int csel  = (sidx & 3) * 8;                              // element offset of 16B chunk
    const unsigned short* gA0 = z1 + (size_t)(rt * BT + srow0) * D + csel;
    const unsigned short* gA1 = gA0 + (size_t)16 * D;
    const unsigned short* gB0 = z2 + (size_t)(cc * BT + srow0) * D + csel;
    const unsigned short* gB1 = gB0 + (size_t)16 * D;
    const int seg0 = wid * 2;

    // ---- fragment read addressing (swizzled) ----
    const int srl   = l15 >> 1;
    const int physr = (((l15 & 1) << 2) | g) ^ srl;
    const int aBase = (wm * 64 + srl) * 64 + physr * 8;   // shorts; + fr*512
    const int bBase = (wn * 32 + srl) * 64 + physr * 8;   // shorts; + fn*512

    f32x4 acc[8][4];
#pragma unroll
    for (int i = 0; i < 8; i++)
#pragma unroll
        for (int j = 0; j < 4; j++) acc[i][j] = (f32x4){0.f, 0.f, 0.f, 0.f};

#define STAGE(t) { const int _b = (t) & 3; const int _k = (t) * BK;               \
        gload16(gA0 + _k, &lds[_b][0][seg0 * 512]);                               \
        gload16(gA1 + _k, &lds[_b][0][(seg0 + 1) * 512]);                         \
        gload16(gB0 + _k, &lds[_b][1][seg0 * 512]);                               \
        gload16(gB1 + _k, &lds[_b][1][(seg0 + 1) * 512]); }

    STAGE(0); STAGE(1); STAGE(2);    // prologue: 12 loads in flight

    for (int t = 0; t < NT; ++t) {
        asm volatile("" ::: "memory");
        __builtin_amdgcn_s_barrier();           // B1: all waves done reading buf[(t+3)&3]
        asm volatile("" ::: "memory");
        if (t < NT - 3) {
            STAGE(t + 3);
            asm volatile("s_waitcnt vmcnt(12)" ::: "memory");   // tile t landed (mine)
        } else if (t == NT - 3) {
            asm volatile("s_waitcnt vmcnt(8)" ::: "memory");
        } else if (t == NT - 2) {
            asm volatile("s_waitcnt vmcnt(4)" ::: "memory");
        } else {
            asm volatile("s_waitcnt vmcnt(0)" ::: "memory");
        }
        __builtin_amdgcn_s_barrier();           // B2: everyone's tile t landed
        asm volatile("" ::: "memory");
        __builtin_amdgcn_sched_barrier(0);

        const unsigned short* Ab = &lds[t & 3][0][0];
        const unsigned short* Bb = &lds[t & 3][1][0];
        bf16x8 af[8], bfv[4];
#pragma unroll
        for (int fr = 0; fr < 8; ++fr)
            af[fr] = *reinterpret_cast<const bf16x8*>(Ab + aBase + fr * 512);
#pragma unroll
        for (int fn = 0; fn < 4; ++fn)
            bfv[fn] = *reinterpret_cast<const bf16x8*>(Bb + bBase + fn * 512);

        __builtin_amdgcn_s_setprio(1);
#pragma unroll
        for (int fr = 0; fr < 8; ++fr)
#pragma unroll
            for (int fn = 0; fn < 4; ++fn)
                acc[fr][fn] = __builtin_amdgcn_mfma_f32_16x16x32_bf16(af[fr], bfv[fn], acc[fr][fn], 0, 0, 0);
        __builtin_amdgcn_s_setprio(0);
    }
#undef STAGE

    // ---- diagonal extraction (u_ii) on the 16 diagonal blocks ----
    if (rt == cc) {
#pragma unroll
        for (int fr = 0; fr < 8; ++fr)
#pragma unroll
            for (int fn = 0; fn < 4; ++fn)
#pragma unroll
                for (int r = 0; r < 4; ++r) {
                    const int rl = wm * 128 + fr * 16 + g * 4 + r;
                    const int cl = wn * 64 + fn * 16 + l15;
                    if (rl == cl) diag[rt * BT + rl] = acc[fr][fn][r];
                }
    }

    // ---- fused LSE partials: per-row max/sum over this 256-col block ----
    __syncthreads();   // full drain; loop done — safe to overlay LDS
    float* mbuf = (float*)&lds[0][0][0];     // [256][4]
    float* sbuf = mbuf + 1024;               // [256][4]

#pragma unroll
    for (int fr = 0; fr < 8; ++fr) {
#pragma unroll
        for (int r = 0; r < 4; ++r) {
            const float v0 = acc[fr][0][r], v1 = acc[fr][1][r];
            const float v2 = acc[fr][2][r], v3 = acc[fr][3][r];
            float m = fmaxf(fmaxf(v0, v1), fmaxf(v2, v3));
            float s = exp2f(v0 - m) + exp2f(v1 - m) + exp2f(v2 - m) + exp2f(v3 - m);
#pragma unroll
            for (int off = 1; off < 16; off <<= 1) {
                const float om = __shfl_xor(m, off);
                const float os = __shfl_xor(s, off);
                const float nm = fmaxf(m, om);
                s = s * exp2f(m - nm) + os * exp2f(om - nm);
                m = nm;
            }
            if (l15 == 0) {
                const int rloc = wm * 128 + fr * 16 + g * 4 + r;
                mbuf[rloc * 4 + wn] = m;
                sbuf[rloc * 4 + wn] = s;
            }
        }
    }
    __syncthreads();
    if (tid < BT) {
        float m = mbuf[tid * 4 + 0];
        m = fmaxf(m, mbuf[tid * 4 + 1]);
        m = fmaxf(m, mbuf[tid * 4 + 2]);
        m = fmaxf(m, mbuf[tid * 4 + 3]);
        float s = 0.f;
#pragma unroll
        for (int q = 0; q < 4; ++q) s += sbuf[tid * 4 + q] * exp2f(mbuf[tid * 4 + q] - m);
        const int grow = rt * BT + tid;
        pmax[grow * NCC + cc] = m;
        psum[grow * NCC + cc] = s;
    }
}

// ---------- 3. per-row partial combine (diag precomputed in gram) ----------
__global__ __launch_bounds__(256) void rowfinal_kernel(const float* __restrict__ pmax,
                                                       const float* __restrict__ psum,
                                                       const float* __restrict__ diag,
                                                       float* __restrict__ contrib) {
    const int i = blockIdx.x * 256 + threadIdx.x;   // row 0..4095
    float4 pm[4], ps[4];
#pragma unroll
    for (int q = 0; q < 4; ++q) {
        pm[q] = reinterpret_cast<const float4*>(pmax + i * NCC)[q];
        ps[q] = reinterpret_cast<const float4*>(psum + i * NCC)[q];
    }
    float m = -INFINITY;
#pragma unroll
    for (int q = 0; q < 4; ++q)
        m = fmaxf(m, fmaxf(fmaxf(pm[q].x, pm[q].y), fmaxf(pm[q].z, pm[q].w)));
    float s = 0.f;
#pragma unroll
    for (int q = 0; q < 4; ++q) {
        s += ps[q].x * exp2f(pm[q].x - m);
        s += ps[q].y * exp2f(pm[q].y - m);
        s += ps[q].z * exp2f(pm[q].z - m);
        s += ps[q].w * exp2f(pm[q].w - m);
    }
    contrib[i] = m + log2f(s) - diag[i];   // exp2-domain LSE minus u_ii
}

// ---------- 4. deterministic final reduce ----------
__global__ __launch_bounds__(256) void final_kernel(const float* __restrict__ contrib,
                                                    float* __restrict__ out) {
    const int tid = threadIdx.x;
    float s = 0.f;
    for (int j = tid; j < NROWS; j += 256) s += contrib[j];
#pragma unroll
    for (int off = 32; off > 0; off >>= 1) s += __shfl_down(s, off);
    __shared__ float red[4];
    const int lane = tid & 63, wid = tid >> 6;
    if (lane == 0) red[wid] = s;
    __syncthreads();
    if (tid == 0) out[0] = (red[0] + red[1] + red[2] + red[3]) * (LN2 / (float)NROWS);
}

extern "C" void kernel_launch(void* const* d_in, const int* in_sizes, int n_in,
                              void* d_out, int out_size, void* d_ws, size_t ws_size,
                              hipStream_t stream) {
    const float* feat = (const float*)d_in[0];
    unsigned short* zn = (unsigned short*)d_ws;
    float* pmax    = (float*)((char*)d_ws + 16777216);
    float* psum    = (float*)((char*)d_ws + 17039360);
    float* diag    = (float*)((char*)d_ws + 17301504);
    float* contrib = (float*)((char*)d_ws + 17317888);
    float* out = (float*)d_out;

    nrm_kernel<<<8192, 256, 0, stream>>>(feat, zn);
    gram_lse_kernel<<<dim3(16, 16), 512, 0, stream>>>(zn, pmax, psum, diag);
    rowfinal_kernel<<<16, 256, 0, stream>>>(pmax, psum, diag, contrib);
    final_kernel<<<1, 256, 0, stream>>>(contrib, out);
}

// Round 4
// 63.695 us; speedup vs baseline: 1.0663x; 1.0663x over previous
//
#include <hip/hip_runtime.h>
#include <hip/hip_bf16.h>

typedef __attribute__((ext_vector_type(8))) short bf16x8;
typedef __attribute__((ext_vector_type(4))) float f32x4;

#define D 1024
#define NROWS 4096          // B
#define SCALE_U 14.426950408889634f   // (1/T) * log2(e)
#define LN2 0.69314718055994530942f
#define NCC 16              // column tiles
#define BT 256              // block tile rows/cols
#define BK 64               // K tile
#define NKT 16              // D/BK

// ---------------- workspace layout ----------------
// zn      : 8192*1024 bf16 (z1 rows pre-scaled by SCALE_U)   @ 0         (16 MiB)
// pmax    : 4096*16 f32                                      @ 16777216  (256 KiB)
// psum    : 4096*16 f32                                      @ 17039360  (256 KiB)
// diag    : 4096 f32                                         @ 17301504  (16 KiB)
// contrib : 4096 f32                                         @ 17317888  (16 KiB)

__device__ __forceinline__ unsigned short f2bf(float x) {
    __hip_bfloat16 h = __float2bfloat16(x);
    return *reinterpret_cast<unsigned short*>(&h);
}
__device__ __forceinline__ void gload16(const unsigned short* g, unsigned short* l) {
    __builtin_amdgcn_global_load_lds((const __attribute__((address_space(1))) void*)g,
                                     (__attribute__((address_space(3))) void*)l, 16, 0, 0);
}

// ---------- 1. row normalize + bf16 cast (z1 scaled by SCALE_U) ----------
__global__ __launch_bounds__(256) void nrm_kernel(const float* __restrict__ feat,
                                                  unsigned short* __restrict__ zn) {
    const int row = blockIdx.x;           // 0..8191
    const int tid = threadIdx.x;          // 256, 4 floats each
    const float4 v = reinterpret_cast<const float4*>(feat + (size_t)row * D)[tid];
    float ss = v.x * v.x + v.y * v.y + v.z * v.z + v.w * v.w;
#pragma unroll
    for (int off = 32; off > 0; off >>= 1) ss += __shfl_down(ss, off);
    __shared__ float red[4];
    const int lane = tid & 63, wid = tid >> 6;
    if (lane == 0) red[wid] = ss;
    __syncthreads();
    const float tot = red[0] + red[1] + red[2] + red[3];
    const float nrm = fmaxf(sqrtf(tot), 1e-8f);
    const float sc = ((row < NROWS) ? SCALE_U : 1.0f) / nrm;
    ushort4 o;
    o.x = f2bf(v.x * sc);
    o.y = f2bf(v.y * sc);
    o.z = f2bf(v.z * sc);
    o.w = f2bf(v.w * sc);
    reinterpret_cast<ushort4*>(zn + (size_t)row * D)[tid] = o;
}

// ---------- 2. Gram (u = logits*log2e), 256² 8-phase schedule + fused LSE ----------
// 8 waves (2M x 4N), wave tile 128x64, BK=64, 2 LDS buffers [buf][op][256][64].
// Per iteration (2 K-tiles): 8 phases, each {ds_read subtile || stage 1 half-tile
// (2 x global_load_lds) || barrier; lgkmcnt(0); setprio+16 MFMA; barrier}.
// vmcnt(6) only at phases 4 and 8. Stage targets = regions consumed >=1 phase ago.
// Swizzle: 16B chunk' = chunk ^ (row&7); pre-swizzled global source, linear dest.
__global__ __launch_bounds__(512, 2) void gram_lse_kernel(const unsigned short* __restrict__ zn,
                                                          float* __restrict__ pmax,
                                                          float* __restrict__ psum,
                                                          float* __restrict__ diag) {
    __shared__ __align__(16) unsigned short lds[65536];   // 128 KiB: [2 buf][2 op][256][64]

    const int rt  = blockIdx.x;       // 0..15 row tile
    const int cc  = blockIdx.y;       // 0..15 col tile
    const int tid = threadIdx.x;
    const int lane = tid & 63;
    const int wid  = tid >> 6;        // 0..7
    const int wm = wid >> 2, wn = wid & 3;
    const int l15 = lane & 15, g = lane >> 4;
    const int xa = l15 & 7;

    const unsigned short* z1 = zn;
    const unsigned short* z2 = zn + (size_t)NROWS * D;

    // staging source addressing (per-lane, inverse-swizzled)
    const int srl = lane >> 3;                       // 0..7
    const int sc8 = ((lane & 7) ^ srl) * 8;
    const unsigned short* gsrcA = z1 + (size_t)(rt * BT + srl) * D + sc8;
    const unsigned short* gsrcB = z2 + (size_t)(cc * BT + srl) * D + sc8;

#define STQ(buf, op, r0, gsrc, k) gload16((gsrc) + (size_t)((r0) + wid * 8) * D + (k), \
        &lds[(((buf) * 2 + (op)) * 256 + (r0) + wid * 8) * 64])
#define SA0(buf,k) do { STQ(buf,0,0,gsrcA,k);   STQ(buf,0,128,gsrcA,k); } while(0)
#define SA1(buf,k) do { STQ(buf,0,64,gsrcA,k);  STQ(buf,0,192,gsrcA,k); } while(0)
#define SB0(buf,k) do { STQ(buf,1,0,gsrcB,k);   STQ(buf,1,64,gsrcB,k);  } while(0)
#define SB1(buf,k) do { STQ(buf,1,128,gsrcB,k); STQ(buf,1,192,gsrcB,k); } while(0)

#define LA(buf,mh,fr,kk) (*reinterpret_cast<const bf16x8*>(&lds[(((buf)*2+0)*256 + wm*128 + ((mh)*4+(fr))*16 + l15)*64 + ((((kk)*4+g)^xa)*8)]))
#define LB(buf,nh,fn,kk) (*reinterpret_cast<const bf16x8*>(&lds[(((buf)*2+1)*256 + wn*64  + ((nh)*2+(fn))*16 + l15)*64 + ((((kk)*4+g)^xa)*8)]))
#define READA(buf, mh) do { \
    a[0]=LA(buf,mh,0,0); a[1]=LA(buf,mh,0,1); a[2]=LA(buf,mh,1,0); a[3]=LA(buf,mh,1,1); \
    a[4]=LA(buf,mh,2,0); a[5]=LA(buf,mh,2,1); a[6]=LA(buf,mh,3,0); a[7]=LA(buf,mh,3,1); } while(0)
#define READB(buf, nh, br) do { \
    br[0]=LB(buf,nh,0,0); br[1]=LB(buf,nh,0,1); br[2]=LB(buf,nh,1,0); br[3]=LB(buf,nh,1,1); } while(0)

#define MM1(mh,nh,fr,br) do { \
  acc[(mh)*4+(fr)][(nh)*2+0] = __builtin_amdgcn_mfma_f32_16x16x32_bf16(a[(fr)*2+0], br[0], acc[(mh)*4+(fr)][(nh)*2+0],0,0,0); \
  acc[(mh)*4+(fr)][(nh)*2+0] = __builtin_amdgcn_mfma_f32_16x16x32_bf16(a[(fr)*2+1], br[1], acc[(mh)*4+(fr)][(nh)*2+0],0,0,0); \
  acc[(mh)*4+(fr)][(nh)*2+1] = __builtin_amdgcn_mfma_f32_16x16x32_bf16(a[(fr)*2+0], br[2], acc[(mh)*4+(fr)][(nh)*2+1],0,0,0); \
  acc[(mh)*4+(fr)][(nh)*2+1] = __builtin_amdgcn_mfma_f32_16x16x32_bf16(a[(fr)*2+1], br[3], acc[(mh)*4+(fr)][(nh)*2+1],0,0,0); } while(0)
#define MMQ(mh,nh,br) do { __builtin_amdgcn_s_setprio(1); \
    MM1(mh,nh,0,br); MM1(mh,nh,1,br); MM1(mh,nh,2,br); MM1(mh,nh,3,br); \
    __builtin_amdgcn_s_setprio(0); } while(0)

#define MIDBAR do { asm volatile("" ::: "memory"); __builtin_amdgcn_s_barrier(); \
    asm volatile("s_waitcnt lgkmcnt(0)" ::: "memory"); } while(0)
#define ENDBAR do { asm volatile("" ::: "memory"); __builtin_amdgcn_s_barrier(); } while(0)

    f32x4 acc[8][4];
#pragma unroll
    for (int i = 0; i < 8; i++)
#pragma unroll
        for (int j = 0; j < 4; j++) acc[i][j] = (f32x4){0.f, 0.f, 0.f, 0.f};

    bf16x8 a[8], b0[4], b1[4];

    // prologue: buf0 <- tile0 (4 half-tiles), buf1 <- tile1 first 3 half-tiles
    SA0(0,0); SB0(0,0); SA1(0,0); SB1(0,0);
    SA0(1,BK); SB0(1,BK); SA1(1,BK);
    asm volatile("s_waitcnt vmcnt(6)" ::: "memory");   // tile0 landed; tile1's 3 HT in flight
    ENDBAR;

    for (int i = 0; i < NKT / 2; ++i) {
        const int k1  = ((2 * i + 1) & (NKT - 1)) * BK;
        const int k02 = ((2 * i + 2) & (NKT - 1)) * BK;
        const int k13 = ((2 * i + 3) & (NKT - 1)) * BK;

        // Ph1: Q(0,0) of t0; stage buf1.B-ht1 (tile t1)
        READA(0,0); READB(0,0,b0);
        SB1(1, k1);
        asm volatile("s_waitcnt lgkmcnt(8)" ::: "memory");
        MIDBAR; MMQ(0,0,b0); ENDBAR;
        // Ph2: Q(0,1); stage buf0.A-ht0 (tile t0+2) — A{q0,q2} consumed at Ph1
        READB(0,1,b1); SA0(0, k02);
        MIDBAR; MMQ(0,1,b1); ENDBAR;
        // Ph3: Q(1,0); stage buf0.B-ht0 — all B consumed by Ph2
        READA(0,1); SB0(0, k02);
        MIDBAR; MMQ(1,0,b0); ENDBAR;
        // Ph4: Q(1,1); stage buf0.A-ht1 — A{q1,q3} consumed at Ph3; vmcnt -> buf1 ready
        SA1(0, k02);
        asm volatile("s_waitcnt vmcnt(6)" ::: "memory");
        MIDBAR; MMQ(1,1,b1); ENDBAR;
        // Ph5: Q(0,0) of t1; stage buf0.B-ht1
        READA(1,0); READB(1,0,b0);
        SB1(0, k02);
        asm volatile("s_waitcnt lgkmcnt(8)" ::: "memory");
        MIDBAR; MMQ(0,0,b0); ENDBAR;
        // Ph6: Q(0,1); stage buf1.A-ht0 (tile t1+2)
        READB(1,1,b1); SA0(1, k13);
        MIDBAR; MMQ(0,1,b1); ENDBAR;
        // Ph7: Q(1,0); stage buf1.B-ht0
        READA(1,1); SB0(1, k13);
        MIDBAR; MMQ(1,0,b0); ENDBAR;
        // Ph8: Q(1,1); stage buf1.A-ht1; vmcnt -> buf0 ready for next iter
        SA1(1, k13);
        asm volatile("s_waitcnt vmcnt(6)" ::: "memory");
        MIDBAR; MMQ(1,1,b1); ENDBAR;
    }
    asm volatile("s_waitcnt vmcnt(0)" ::: "memory");   // drain tail stages before LDS reuse
    __syncthreads();

    // ---- diagonal extraction (u_ii) on the 16 diagonal blocks ----
    if (rt == cc) {
#pragma unroll
        for (int fr = 0; fr < 8; ++fr)
#pragma unroll
            for (int fn = 0; fn < 4; ++fn)
#pragma unroll
                for (int r = 0; r < 4; ++r) {
                    const int rl = wm * 128 + fr * 16 + g * 4 + r;
                    const int cl = wn * 64 + fn * 16 + l15;
                    if (rl == cl) diag[rt * BT + rl] = acc[fr][fn][r];
                }
    }

    // ---- fused LSE partials over this 256-col block ----
    float* mbuf = (float*)&lds[0];        // [256][4]
    float* sbuf = mbuf + 1024;            // [256][4]
#pragma unroll
    for (int fr = 0; fr < 8; ++fr) {
#pragma unroll
        for (int r = 0; r < 4; ++r) {
            const float v0 = acc[fr][0][r], v1 = acc[fr][1][r];
            const float v2 = acc[fr][2][r], v3 = acc[fr][3][r];
            float m = fmaxf(fmaxf(v0, v1), fmaxf(v2, v3));
            float s = exp2f(v0 - m) + exp2f(v1 - m) + exp2f(v2 - m) + exp2f(v3 - m);
#pragma unroll
            for (int off = 1; off < 16; off <<= 1) {
                const float om = __shfl_xor(m, off);
                const float os = __shfl_xor(s, off);
                const float nm = fmaxf(m, om);
                s = s * exp2f(m - nm) + os * exp2f(om - nm);
                m = nm;
            }
            if (l15 == 0) {
                const int rloc = wm * 128 + fr * 16 + g * 4 + r;
                mbuf[rloc * 4 + wn] = m;
                sbuf[rloc * 4 + wn] = s;
            }
        }
    }
    __syncthreads();
    if (tid < BT) {
        float m = mbuf[tid * 4 + 0];
        m = fmaxf(m, mbuf[tid * 4 + 1]);
        m = fmaxf(m, mbuf[tid * 4 + 2]);
        m = fmaxf(m, mbuf[tid * 4 + 3]);
        float s = 0.f;
#pragma unroll
        for (int q = 0; q < 4; ++q) s += sbuf[tid * 4 + q] * exp2f(mbuf[tid * 4 + q] - m);
        const int grow = rt * BT + tid;
        pmax[grow * NCC + cc] = m;
        psum[grow * NCC + cc] = s;
    }
}

// ---------- 3. per-row partial combine (diag precomputed in gram) ----------
__global__ __launch_bounds__(256) void rowfinal_kernel(const float* __restrict__ pmax,
                                                       const float* __restrict__ psum,
                                                       const float* __restrict__ diag,
                                                       float* __restrict__ contrib) {
    const int i = blockIdx.x * 256 + threadIdx.x;   // row 0..4095
    float4 pm[4], ps[4];
#pragma unroll
    for (int q = 0; q < 4; ++q) {
        pm[q] = reinterpret_cast<const float4*>(pmax + i * NCC)[q];
        ps[q] = reinterpret_cast<const float4*>(psum + i * NCC)[q];
    }
    float m = -INFINITY;
#pragma unroll
    for (int q = 0; q < 4; ++q)
        m = fmaxf(m, fmaxf(fmaxf(pm[q].x, pm[q].y), fmaxf(pm[q].z, pm[q].w)));
    float s = 0.f;
#pragma unroll
    for (int q = 0; q < 4; ++q) {
        s += ps[q].x * exp2f(pm[q].x - m);
        s += ps[q].y * exp2f(pm[q].y - m);
        s += ps[q].z * exp2f(pm[q].z - m);
        s += ps[q].w * exp2f(pm[q].w - m);
    }
    contrib[i] = m + log2f(s) - diag[i];   // exp2-domain LSE minus u_ii
}

// ---------- 4. deterministic final reduce ----------
__global__ __launch_bounds__(256) void final_kernel(const float* __restrict__ contrib,
                                                    float* __restrict__ out) {
    const int tid = threadIdx.x;
    float s = 0.f;
    for (int j = tid; j < NROWS; j += 256) s += contrib[j];
#pragma unroll
    for (int off = 32; off > 0; off >>= 1) s += __shfl_down(s, off);
    __shared__ float red[4];
    const int lane = tid & 63, wid = tid >> 6;
    if (lane == 0) red[wid] = s;
    __syncthreads();
    if (tid == 0) out[0] = (red[0] + red[1] + red[2] + red[3]) * (LN2 / (float)NROWS);
}

extern "C" void kernel_launch(void* const* d_in, const int* in_sizes, int n_in,
                              void* d_out, int out_size, void* d_ws, size_t ws_size,
                              hipStream_t stream) {
    const float* feat = (const float*)d_in[0];
    unsigned short* zn = (unsigned short*)d_ws;
    float* pmax    = (float*)((char*)d_ws + 16777216);
    float* psum    = (float*)((char*)d_ws + 17039360);
    float* diag    = (float*)((char*)d_ws + 17301504);
    float* contrib = (float*)((char*)d_ws + 17317888);
    float* out = (float*)d_out;

    nrm_kernel<<<8192, 256, 0, stream>>>(feat, zn);
    gram_lse_kernel<<<dim3(16, 16), 512, 0, stream>>>(zn, pmax, psum, diag);
    rowfinal_kernel<<<16, 256, 0, stream>>>(pmax, psum, diag, contrib);
    final_kernel<<<1, 256, 0, stream>>>(contrib, out);
}